// Round 2
// baseline (434.004 us; speedup 1.0000x reference)
//
#include <hip/hip_runtime.h>
#include <hip/hip_bf16.h>

typedef float f32x4 __attribute__((ext_vector_type(4)));
typedef short s16x8 __attribute__((ext_vector_type(8)));
typedef unsigned int u32;

#define LOG2E 1.4426950408889634f
#define NEGINF (-1e30f)

__device__ __forceinline__ unsigned short f2bf(float f) {
    __hip_bfloat16 h = __float2bfloat16(f);
    unsigned short u;
    __builtin_memcpy(&u, &h, 2);
    return u;
}

// ---------------------------------------------------------------------------
// Pre-kernel: fused[wh][c][r] = (mask[w][c][r] + bias_table[rel_index[c][r]][h]) * log2(e)
// Layout: [512][49][52] f32 (r-stride padded to 52 so r0 = 16*mr + 4*g is 16B-aligned)
// ---------------------------------------------------------------------------
__global__ void fuse_bias_mask(const float* __restrict__ bias_table,
                               const float* __restrict__ mask,
                               const int*   __restrict__ rel_index,
                               float*       __restrict__ fused) {
    int tid = blockIdx.x * 256 + threadIdx.x;
    const int total = 512 * 2401;
    if (tid >= total) return;
    int wh  = tid / 2401;
    int rem = tid - wh * 2401;          // = c*49 + r
    int c   = rem / 49;
    int w = wh >> 3, h = wh & 7;
    int idx = rel_index[rem];
    float v = (mask[w * 2401 + rem] + bias_table[idx * 8 + h]) * LOG2E;
    fused[((long)wh * 49 + c) * 52 + (rem - c * 49)] = v;
}

// ---------------------------------------------------------------------------
// Main kernel: grid 2048, 256 thr (4 waves). Each block: 2 windows; each wave:
// 2 heads per window = 4 head-tasks, software-pipelined: next task's QK raw
// f32 loads are issued as soon as the current task's conversions free the
// registers, so their HBM latency hides under MFMA+softmax+PV (~2K cycles).
// Within a task, S is computed per query-column tile (nc) so the compiler can
// overlap nc+1's MFMAs with nc's softmax VALU. No __syncthreads anywhere.
// ---------------------------------------------------------------------------
template<bool FUSED>
__global__ __launch_bounds__(256, 3)
void win_attn(const float* __restrict__ x,
              const float* __restrict__ bias_table,
              const float* __restrict__ mask,
              const int*   __restrict__ rel_index,
              const float* __restrict__ fused,
              float*       __restrict__ out) {
    __shared__ char Plds[4][8192];      // per-wave P tile: [64 c][64 j] bf16, XOR-swizzled
    const int tid  = threadIdx.x;
    const int wav  = tid >> 6;
    const int lane = tid & 63;
    const int li   = lane & 15;
    const int g    = lane >> 4;
    char* P = &Plds[wav][0];
    const float scale2 = 0.17677669529663689f * LOG2E;  // hd^-0.5 * log2(e)

    const int b0 = blockIdx.x * 2;

    // prefetch registers: raw[t][half] = f32x4 of row 16t+li, cols g*8..g*8+7
    f32x4 raw[4][2];

    auto issue_raw = [&](int task) {
        int it = task >> 1, hh = task & 1;
        int b = b0 + it, h = wav * 2 + hh;
        const float* xh = x + (long)b * (49 * 256) + h * 32;
        #pragma unroll
        for (int t = 0; t < 4; ++t) {
            int row = t * 16 + li;
            if (row < 49) {
                const f32x4* p = (const f32x4*)(xh + (long)row * 256 + g * 8);
                raw[t][0] = p[0];
                raw[t][1] = p[1];
            } else {
                raw[t][0] = f32x4{0.f, 0.f, 0.f, 0.f};
                raw[t][1] = f32x4{0.f, 0.f, 0.f, 0.f};
            }
        }
    };

    issue_raw(0);

    #pragma unroll 1
    for (int task = 0; task < 4; ++task) {
        const int it = task >> 1, hh = task & 1;
        const int b = b0 + it, h = wav * 2 + hh, w = b & 63;
        const float* xh = x + (long)b * (49 * 256) + h * 32;

        // ---- V loads first (lines already in L1/L2 from the raw prefetch) ----
        float vraw[2][2][8];
        #pragma unroll
        for (int nd = 0; nd < 2; ++nd)
            #pragma unroll
            for (int kt = 0; kt < 2; ++kt) {
                int d = li + 16 * nd;
                #pragma unroll
                for (int jj = 0; jj < 8; ++jj) {
                    int j = 32 * kt + 8 * g + jj;
                    vraw[nd][kt][jj] = (j < 49) ? xh[(long)j * 256 + d] : 0.f;
                }
            }

        // ---- convert prefetched raws -> Fh (trunc) / Fl (RNE residual) ----
        // (no vmcnt stall in steady state: loads were issued one task ago)
        s16x8 Fh[4], Fl[4];
        #pragma unroll
        for (int t = 0; t < 4; ++t) {
            u32 hp[4], lp[4];
            #pragma unroll
            for (int pq = 0; pq < 4; ++pq) {
                float f0 = raw[t][pq >> 1][(pq & 1) * 2 + 0];
                float f1 = raw[t][pq >> 1][(pq & 1) * 2 + 1];
                u32 u0 = __float_as_uint(f0), u1 = __float_as_uint(f1);
                hp[pq] = (u0 >> 16) | (u1 & 0xFFFF0000u);      // pair hi pack (v_perm)
                float r0 = f0 - __uint_as_float(u0 & 0xFFFF0000u);
                float r1 = f1 - __uint_as_float(u1 & 0xFFFF0000u);
                lp[pq] = (u32)f2bf(r0) | ((u32)f2bf(r1) << 16); // pair lo pack (cvt_pk)
            }
            __builtin_memcpy(&Fh[t], hp, 16);
            __builtin_memcpy(&Fl[t], lp, 16);
        }

        // ---- V -> bf16 frags ----
        s16x8 Vf[2][2];
        #pragma unroll
        for (int nd = 0; nd < 2; ++nd)
            #pragma unroll
            for (int kt = 0; kt < 2; ++kt) {
                s16x8 vv;
                #pragma unroll
                for (int jj = 0; jj < 8; ++jj)
                    vv[jj] = (short)f2bf(vraw[nd][kt][jj]);
                Vf[nd][kt] = vv;
            }

        // ---- prefetch next task's QK raws (raw[] regs are free again) ----
        if (task < 3) issue_raw(task + 1);

        // ---- per column-tile: 12 S-MFMAs then softmax; nc+1 MFMAs overlap nc VALU ----
        const int wh = w * 8 + h;
        #pragma unroll
        for (int nc = 0; nc < 4; ++nc) {
            __builtin_amdgcn_s_setprio(1);
            f32x4 a[4];
            #pragma unroll
            for (int mr = 0; mr < 4; ++mr) {
                f32x4 t = f32x4{0.f, 0.f, 0.f, 0.f};
                t = __builtin_amdgcn_mfma_f32_16x16x32_bf16(Fh[mr], Fh[nc], t, 0, 0, 0);
                t = __builtin_amdgcn_mfma_f32_16x16x32_bf16(Fh[mr], Fl[nc], t, 0, 0, 0);
                t = __builtin_amdgcn_mfma_f32_16x16x32_bf16(Fl[mr], Fh[nc], t, 0, 0, 0);
                a[mr] = t;
            }
            __builtin_amdgcn_s_setprio(0);

            int c = li + 16 * nc;
            int cidx = min(c, 48);                 // c>=49: garbage queries, clamp (finite)
            if (FUSED) {
                const float* fb = fused + ((long)wh * 49 + cidx) * 52;
                #pragma unroll
                for (int mr = 0; mr < 3; ++mr) {
                    f32x4 tt = *(const f32x4*)(fb + 16 * mr + 4 * g);
                    #pragma unroll
                    for (int i = 0; i < 4; ++i)
                        a[mr][i] = a[mr][i] * scale2 + tt[i];
                }
                float t48 = fb[48];
                a[3][0] = (g == 0) ? a[3][0] * scale2 + t48 : NEGINF;
                a[3][1] = NEGINF; a[3][2] = NEGINF; a[3][3] = NEGINF;
            } else {
                const int base = cidx * 49;
                #pragma unroll
                for (int mr = 0; mr < 3; ++mr)
                    #pragma unroll
                    for (int i = 0; i < 4; ++i) {
                        int r = 16 * mr + 4 * g + i;
                        float bm = (mask[w * 2401 + base + r]
                                    + bias_table[rel_index[base + r] * 8 + h]) * LOG2E;
                        a[mr][i] = a[mr][i] * scale2 + bm;
                    }
                float bm48 = (mask[w * 2401 + base + 48]
                              + bias_table[rel_index[base + 48] * 8 + h]) * LOG2E;
                a[3][0] = (g == 0) ? a[3][0] * scale2 + bm48 : NEGINF;
                a[3][1] = NEGINF; a[3][2] = NEGINF; a[3][3] = NEGINF;
            }

            // row max over 64 keys (max3-friendly tree + xor-shuffles)
            float m = fmaxf(fmaxf(fmaxf(a[0][0], a[0][1]), fmaxf(a[0][2], a[0][3])),
                            fmaxf(fmaxf(a[1][0], a[1][1]), fmaxf(a[1][2], a[1][3])));
            m = fmaxf(m, fmaxf(fmaxf(fmaxf(a[2][0], a[2][1]), fmaxf(a[2][2], a[2][3])),
                               fmaxf(fmaxf(a[3][0], a[3][1]), fmaxf(a[3][2], a[3][3]))));
            m = fmaxf(m, __shfl_xor(m, 16));
            m = fmaxf(m, __shfl_xor(m, 32));

            float s = 0.f;
            #pragma unroll
            for (int mr = 0; mr < 4; ++mr)
                #pragma unroll
                for (int i = 0; i < 4; ++i) {
                    float p = __builtin_amdgcn_exp2f(a[mr][i] - m);
                    a[mr][i] = p;
                    s += p;
                }
            s += __shfl_xor(s, 16);
            s += __shfl_xor(s, 32);
            float sinv = __builtin_amdgcn_rcpf(s);

            // normalized P row -> LDS bf16, byte ^= ((c&7)<<4) swizzle
            char* rowp = P + c * 128;
            unsigned sw = ((unsigned)(c & 7)) << 4;
            #pragma unroll
            for (int mr = 0; mr < 4; ++mr) {
                u32 p0 = (u32)f2bf(a[mr][0] * sinv) | ((u32)f2bf(a[mr][1] * sinv) << 16);
                u32 p1 = (u32)f2bf(a[mr][2] * sinv) | ((u32)f2bf(a[mr][3] * sinv) << 16);
                uint2 v; v.x = p0; v.y = p1;
                *(uint2*)(rowp + (((unsigned)(32 * mr + 8 * g)) ^ sw)) = v;
            }
        }

        // ---- O = P V : A = P from LDS (row q=li+16mc, k j=32kt+8g+jj), B = Vf ----
        f32x4 o[4][2];
        #pragma unroll
        for (int mc = 0; mc < 4; ++mc)
            #pragma unroll
            for (int nd = 0; nd < 2; ++nd) o[mc][nd] = f32x4{0.f, 0.f, 0.f, 0.f};
        __builtin_amdgcn_s_setprio(1);
        #pragma unroll
        for (int mc = 0; mc < 4; ++mc) {
            int c2 = li + 16 * mc;
            char* rowp = P + c2 * 128;
            unsigned sw = ((unsigned)(c2 & 7)) << 4;
            #pragma unroll
            for (int kt = 0; kt < 2; ++kt) {
                s16x8 pa = *(const s16x8*)(rowp + (((unsigned)(64 * kt + 16 * g)) ^ sw));
                #pragma unroll
                for (int nd = 0; nd < 2; ++nd)
                    o[mc][nd] = __builtin_amdgcn_mfma_f32_16x16x32_bf16(pa, Vf[nd][kt], o[mc][nd], 0, 0, 0);
            }
        }
        __builtin_amdgcn_s_setprio(0);

        // ---- store (nontemporal: out is never re-read; keep L2/L3 for x/fused) ----
        float* ob = out + (long)b * (49 * 256) + h * 32;
        #pragma unroll
        for (int mc = 0; mc < 4; ++mc) {
            int cbase = 16 * mc + 4 * g;
            #pragma unroll
            for (int i = 0; i < 4; ++i) {
                int crow = cbase + i;
                if (crow < 49) {
                    #pragma unroll
                    for (int nd = 0; nd < 2; ++nd)
                        __builtin_nontemporal_store(o[mc][nd][i],
                            &ob[(long)crow * 256 + 16 * nd + li]);
                }
            }
        }
    }
}

extern "C" void kernel_launch(void* const* d_in, const int* in_sizes, int n_in,
                              void* d_out, int out_size, void* d_ws, size_t ws_size,
                              hipStream_t stream) {
    const float* x          = (const float*)d_in[0];
    const float* bias_table = (const float*)d_in[1];
    const float* mask       = (const float*)d_in[2];
    const int*   rel_index  = (const int*)d_in[3];
    float* out   = (float*)d_out;
    float* fused = (float*)d_ws;

    const size_t need = (size_t)512 * 49 * 52 * 4;   // 5.2 MB fused (mask+bias)*log2e
    if (ws_size >= need) {
        const int total = 512 * 2401;
        fuse_bias_mask<<<(total + 255) / 256, 256, 0, stream>>>(bias_table, mask, rel_index, fused);
        win_attn<true><<<2048, 256, 0, stream>>>(x, bias_table, mask, rel_index, fused, out);
    } else {
        win_attn<false><<<2048, 256, 0, stream>>>(x, bias_table, mask, rel_index, nullptr, out);
    }
}

// Round 3
// 378.989 us; speedup vs baseline: 1.1452x; 1.1452x over previous
//
#include <hip/hip_runtime.h>
#include <hip/hip_bf16.h>

typedef float f32x4 __attribute__((ext_vector_type(4)));
typedef short s16x8 __attribute__((ext_vector_type(8)));
typedef unsigned int u32;

#define LOG2E 1.4426950408889634f
#define NEGINF (-1e30f)

// f32 pair -> packed bf16 (RNE), single VALU op. Low half = a, high half = b.
__device__ __forceinline__ u32 cvt_pk_bf16(float a, float b) {
    u32 r;
    asm("v_cvt_pk_bf16_f32 %0, %1, %2" : "=v"(r) : "v"(a), "v"(b));
    return r;
}

// ---------------------------------------------------------------------------
// Pre-kernel: fused[wh][c][r] = (mask[w][c][r] + bias_table[rel_index[c][r]][h]) * log2(e)
// Layout: [512][49][52] f32 (r-stride padded to 52 so r0 = 16*mr + 4*g is 16B-aligned)
// ---------------------------------------------------------------------------
__global__ void fuse_bias_mask(const float* __restrict__ bias_table,
                               const float* __restrict__ mask,
                               const int*   __restrict__ rel_index,
                               float*       __restrict__ fused) {
    int tid = blockIdx.x * 256 + threadIdx.x;
    const int total = 512 * 2401;
    if (tid >= total) return;
    int wh  = tid / 2401;
    int rem = tid - wh * 2401;          // = c*49 + r
    int c   = rem / 49;
    int w = wh >> 3, h = wh & 7;
    int idx = rel_index[rem];
    float v = (mask[w * 2401 + rem] + bias_table[idx * 8 + h]) * LOG2E;
    fused[((long)wh * 49 + c) * 52 + (rem - c * 49)] = v;
}

// ---------------------------------------------------------------------------
// Main kernel: grid 4096 (1 window-batch/block), 4 waves; each wave: 2 heads.
// Per head-task:
//   1. issue QK row loads (8x dwordx4) and V column loads (32x dword)
//   2. convert QK raws -> Fh/Fl (hi/lo bf16 split) while V flies
//   3. convert V -> bf16 frags (latency hidden under step 2)
//   4. per query-column tile nc: 12 S-MFMAs, wave softmax, P -> swizzled LDS
//   5. O = P V (A-frags from LDS), store f32
// All f32->bf16 via v_cvt_pk_bf16_f32 (1 op / 2 values). No __syncthreads.
// LDS: 49 P rows/wave (junk queries clamped both sides) = 24.5 KB/block.
// ---------------------------------------------------------------------------
template<bool FUSED>
__global__ __launch_bounds__(256, 3)
void win_attn(const float* __restrict__ x,
              const float* __restrict__ bias_table,
              const float* __restrict__ mask,
              const int*   __restrict__ rel_index,
              const float* __restrict__ fused,
              float*       __restrict__ out) {
    __shared__ char Plds[4][49 * 128];  // per-wave P tile, XOR-swizzled rows
    const int tid  = threadIdx.x;
    const int wav  = tid >> 6;
    const int lane = tid & 63;
    const int li   = lane & 15;
    const int g    = lane >> 4;
    char* P = &Plds[wav][0];
    const float scale2 = 0.17677669529663689f * LOG2E;  // hd^-0.5 * log2(e)

    const int b = blockIdx.x;
    const int w = b & 63;               // b = img*64 + w
    const float* xb = x + (long)b * (49 * 256);

    #pragma unroll 1
    for (int hh = 0; hh < 2; ++hh) {
        const int h = wav * 2 + hh;
        const float* xh = xb + h * 32;

        // ---- 1a. QK row loads: rows 16t+li, cols g*8..g*8+7 ----
        f32x4 raw[4][2];
        #pragma unroll
        for (int t = 0; t < 4; ++t) {
            int row = t * 16 + li;
            if (row < 49) {
                const f32x4* p = (const f32x4*)(xh + (long)row * 256 + g * 8);
                raw[t][0] = p[0];
                raw[t][1] = p[1];
            } else {
                raw[t][0] = f32x4{0.f, 0.f, 0.f, 0.f};
                raw[t][1] = f32x4{0.f, 0.f, 0.f, 0.f};
            }
        }

        // ---- 1b. V column loads: V[j=32kt+8g+jj][d=li+16nd] (L2 hits; consumed late) ----
        float vraw[2][2][8];
        #pragma unroll
        for (int nd = 0; nd < 2; ++nd)
            #pragma unroll
            for (int kt = 0; kt < 2; ++kt) {
                int d = li + 16 * nd;
                #pragma unroll
                for (int jj = 0; jj < 8; ++jj) {
                    int j = 32 * kt + 8 * g + jj;
                    vraw[nd][kt][jj] = (j < 49) ? xh[(long)j * 256 + d] : 0.f;
                }
            }

        // ---- 2. QK raws -> Fh (truncated hi) / Fl (RNE residual) ----
        s16x8 Fh[4], Fl[4];
        #pragma unroll
        for (int t = 0; t < 4; ++t) {
            u32 hp[4], lp[4];
            #pragma unroll
            for (int pq = 0; pq < 4; ++pq) {
                float f0 = raw[t][pq >> 1][(pq & 1) * 2 + 0];
                float f1 = raw[t][pq >> 1][(pq & 1) * 2 + 1];
                u32 u0 = __float_as_uint(f0), u1 = __float_as_uint(f1);
                hp[pq] = (u0 >> 16) | (u1 & 0xFFFF0000u);          // v_perm idiom
                float r0 = f0 - __uint_as_float(u0 & 0xFFFF0000u);
                float r1 = f1 - __uint_as_float(u1 & 0xFFFF0000u);
                lp[pq] = cvt_pk_bf16(r0, r1);
            }
            __builtin_memcpy(&Fh[t], hp, 16);
            __builtin_memcpy(&Fl[t], lp, 16);
        }

        // ---- 3. V -> bf16 frags ----
        s16x8 Vf[2][2];
        #pragma unroll
        for (int nd = 0; nd < 2; ++nd)
            #pragma unroll
            for (int kt = 0; kt < 2; ++kt) {
                u32 vp[4];
                #pragma unroll
                for (int p = 0; p < 4; ++p)
                    vp[p] = cvt_pk_bf16(vraw[nd][kt][2 * p], vraw[nd][kt][2 * p + 1]);
                __builtin_memcpy(&Vf[nd][kt], vp, 16);
            }

        // ---- 4. per column tile: S-MFMAs then softmax (nc+1 MFMAs overlap nc VALU) ----
        const int wh = w * 8 + h;
        #pragma unroll
        for (int nc = 0; nc < 4; ++nc) {
            __builtin_amdgcn_s_setprio(1);
            f32x4 a[4];
            #pragma unroll
            for (int mr = 0; mr < 4; ++mr) {
                f32x4 t = f32x4{0.f, 0.f, 0.f, 0.f};
                t = __builtin_amdgcn_mfma_f32_16x16x32_bf16(Fh[mr], Fh[nc], t, 0, 0, 0);
                t = __builtin_amdgcn_mfma_f32_16x16x32_bf16(Fh[mr], Fl[nc], t, 0, 0, 0);
                t = __builtin_amdgcn_mfma_f32_16x16x32_bf16(Fl[mr], Fh[nc], t, 0, 0, 0);
                a[mr] = t;
            }
            __builtin_amdgcn_s_setprio(0);

            int c = li + 16 * nc;
            int cidx = min(c, 48);                 // junk queries read row 48 (finite)
            if (FUSED) {
                const float* fb = fused + ((long)wh * 49 + cidx) * 52;
                #pragma unroll
                for (int mr = 0; mr < 3; ++mr) {
                    f32x4 tt = *(const f32x4*)(fb + 16 * mr + 4 * g);
                    #pragma unroll
                    for (int i = 0; i < 4; ++i)
                        a[mr][i] = a[mr][i] * scale2 + tt[i];
                }
                float t48 = fb[48];
                a[3][0] = (g == 0) ? a[3][0] * scale2 + t48 : NEGINF;
                a[3][1] = NEGINF; a[3][2] = NEGINF; a[3][3] = NEGINF;
            } else {
                const int base = cidx * 49;
                #pragma unroll
                for (int mr = 0; mr < 3; ++mr)
                    #pragma unroll
                    for (int i = 0; i < 4; ++i) {
                        int r = 16 * mr + 4 * g + i;
                        float bm = (mask[w * 2401 + base + r]
                                    + bias_table[rel_index[base + r] * 8 + h]) * LOG2E;
                        a[mr][i] = a[mr][i] * scale2 + bm;
                    }
                float bm48 = (mask[w * 2401 + base + 48]
                              + bias_table[rel_index[base + 48] * 8 + h]) * LOG2E;
                a[3][0] = (g == 0) ? a[3][0] * scale2 + bm48 : NEGINF;
                a[3][1] = NEGINF; a[3][2] = NEGINF; a[3][3] = NEGINF;
            }

            // row max over 64 keys
            float m = fmaxf(fmaxf(fmaxf(a[0][0], a[0][1]), fmaxf(a[0][2], a[0][3])),
                            fmaxf(fmaxf(a[1][0], a[1][1]), fmaxf(a[1][2], a[1][3])));
            m = fmaxf(m, fmaxf(fmaxf(fmaxf(a[2][0], a[2][1]), fmaxf(a[2][2], a[2][3])),
                               fmaxf(fmaxf(a[3][0], a[3][1]), fmaxf(a[3][2], a[3][3]))));
            m = fmaxf(m, __shfl_xor(m, 16));
            m = fmaxf(m, __shfl_xor(m, 32));

            float s = 0.f;
            #pragma unroll
            for (int mr = 0; mr < 4; ++mr)
                #pragma unroll
                for (int i = 0; i < 4; ++i) {
                    float p = __builtin_amdgcn_exp2f(a[mr][i] - m);
                    a[mr][i] = p;
                    s += p;
                }
            s += __shfl_xor(s, 16);
            s += __shfl_xor(s, 32);
            float sinv = __builtin_amdgcn_rcpf(s);

            // normalized P row -> LDS bf16, byte ^= ((c&7)<<4) swizzle; rows 0..48 only
            if (c <= 48) {
                char* rowp = P + c * 128;
                u32 sw = ((u32)(c & 7)) << 4;
                #pragma unroll
                for (int mr = 0; mr < 4; ++mr) {
                    uint2 v;
                    v.x = cvt_pk_bf16(a[mr][0] * sinv, a[mr][1] * sinv);
                    v.y = cvt_pk_bf16(a[mr][2] * sinv, a[mr][3] * sinv);
                    *(uint2*)(rowp + (((u32)(32 * mr + 8 * g)) ^ sw)) = v;
                }
            }
        }

        // ---- 5. O = P V : A = P from LDS (row q=li+16mc clamped, k j=32kt+8g+jj) ----
        f32x4 o[4][2];
        #pragma unroll
        for (int mc = 0; mc < 4; ++mc)
            #pragma unroll
            for (int nd = 0; nd < 2; ++nd) o[mc][nd] = f32x4{0.f, 0.f, 0.f, 0.f};
        __builtin_amdgcn_s_setprio(1);
        #pragma unroll
        for (int mc = 0; mc < 4; ++mc) {
            int cr = min(li + 16 * mc, 48);        // junk queries read row 48
            char* rowp = P + cr * 128;
            u32 sw = ((u32)(cr & 7)) << 4;
            #pragma unroll
            for (int kt = 0; kt < 2; ++kt) {
                s16x8 pa = *(const s16x8*)(rowp + (((u32)(64 * kt + 16 * g)) ^ sw));
                #pragma unroll
                for (int nd = 0; nd < 2; ++nd)
                    o[mc][nd] = __builtin_amdgcn_mfma_f32_16x16x32_bf16(pa, Vf[nd][kt], o[mc][nd], 0, 0, 0);
            }
        }
        __builtin_amdgcn_s_setprio(0);

        // ---- store (normal stores: let L2 merge the 8 heads' 128B chunks) ----
        float* ob = out + (long)b * (49 * 256) + h * 32;
        #pragma unroll
        for (int mc = 0; mc < 4; ++mc) {
            int cbase = 16 * mc + 4 * g;
            #pragma unroll
            for (int i = 0; i < 4; ++i) {
                int crow = cbase + i;
                if (crow < 49) {
                    #pragma unroll
                    for (int nd = 0; nd < 2; ++nd)
                        ob[(long)crow * 256 + 16 * nd + li] = o[mc][nd][i];
                }
            }
        }
    }
}

extern "C" void kernel_launch(void* const* d_in, const int* in_sizes, int n_in,
                              void* d_out, int out_size, void* d_ws, size_t ws_size,
                              hipStream_t stream) {
    const float* x          = (const float*)d_in[0];
    const float* bias_table = (const float*)d_in[1];
    const float* mask       = (const float*)d_in[2];
    const int*   rel_index  = (const int*)d_in[3];
    float* out   = (float*)d_out;
    float* fused = (float*)d_ws;

    const size_t need = (size_t)512 * 49 * 52 * 4;   // 5.2 MB fused (mask+bias)*log2e
    if (ws_size >= need) {
        const int total = 512 * 2401;
        fuse_bias_mask<<<(total + 255) / 256, 256, 0, stream>>>(bias_table, mask, rel_index, fused);
        win_attn<true><<<4096, 256, 0, stream>>>(x, bias_table, mask, rel_index, fused, out);
    } else {
        win_attn<false><<<4096, 256, 0, stream>>>(x, bias_table, mask, rel_index, nullptr, out);
    }
}